// Round 14
// baseline (109.962 us; speedup 1.0000x reference)
//
#include <hip/hip_runtime.h>

#define NPTS 8192
#define KNN  15
#define G    64
#define NC   (G * G)           // 4096 cells
#define TPB_A 1024
#define WPB  8
#define TPB  (WPB * 64)        // 512 threads, 1 query per wave
#define SEG  64

// d_ws layout (byte offsets)
#define WS_CS    16            // u16[4104] cell starts (4097 used)
#define WS_SIDX  8224          // u16[8192]: orig_idx | label<<13
#define WS_CRD   24608         // float2[8192] cell-sorted coords
#define WS_SR    90144         // u8[4096] per-cell certified scan radius

__device__ __forceinline__ unsigned int bitonic_sort_u32(unsigned int v, int lane) {
#pragma unroll
  for (int k = 2; k <= 64; k <<= 1) {
#pragma unroll
    for (int j = k >> 1; j > 0; j >>= 1) {
      unsigned int o = __shfl_xor(v, j, 64);
      bool keep_min = ((lane & k) == 0) == ((lane & j) == 0);
      unsigned int lo = (v < o) ? v : o;
      unsigned int hi = (v < o) ? o : v;
      v = keep_min ? lo : hi;
    }
  }
  return v;
}

// ---------------- Kernel A: grid build + per-cell radius ----------------
__global__ __launch_bounds__(TPB_A)
void build_kernel(const float* __restrict__ x, const int* __restrict__ y,
                  unsigned char* __restrict__ ws) {
  __shared__ unsigned int hist[NC];     // counts -> starts -> next-free
  __shared__ float rb[64];              // per-wave bbox partials
  __shared__ float hdr[4];
  __shared__ unsigned int wsum[16];     // per-wave scan totals

  const int t = threadIdx.x;
  const int lane = t & 63, wv = t >> 6;

  float px[8], py[8];
  float mnx = 3e38f, mxx = -3e38f, mny = 3e38f, mxy = -3e38f;
#pragma unroll
  for (int i = 0; i < 8; ++i) {
    float2 p = ((const float2*)x)[t + i * TPB_A];
    px[i] = p.x; py[i] = p.y;
    mnx = fminf(mnx, p.x); mxx = fmaxf(mxx, p.x);
    mny = fminf(mny, p.y); mxy = fmaxf(mxy, p.y);
  }
#pragma unroll
  for (int j = 32; j >= 1; j >>= 1) {
    mnx = fminf(mnx, __shfl_xor(mnx, j, 64));
    mxx = fmaxf(mxx, __shfl_xor(mxx, j, 64));
    mny = fminf(mny, __shfl_xor(mny, j, 64));
    mxy = fmaxf(mxy, __shfl_xor(mxy, j, 64));
  }
  if (lane == 0) { rb[wv] = mnx; rb[16 + wv] = mxx; rb[32 + wv] = mny; rb[48 + wv] = mxy; }
  for (int c = t; c < NC; c += TPB_A) hist[c] = 0;
  __syncthreads();
  if (t == 0) {
    float a = rb[0], b = rb[16], c2 = rb[32], d = rb[48];
    for (int i = 1; i < 16; ++i) {
      a = fminf(a, rb[i]); b = fmaxf(b, rb[16 + i]);
      c2 = fminf(c2, rb[32 + i]); d = fmaxf(d, rb[48 + i]);
    }
    float sp = fmaxf(b - a, d - c2) * (1.0f + 1e-6f) + 1e-6f;   // square cells
    hdr[0] = a; hdr[1] = c2; hdr[2] = (float)G / sp; hdr[3] = sp / (float)G;
    float* h = (float*)ws; h[0] = hdr[0]; h[1] = hdr[1]; h[2] = hdr[2]; h[3] = hdr[3];
  }
  __syncthreads();
  const float xmin = hdr[0], ymin = hdr[1], invw = hdr[2];

  int cell[8];
#pragma unroll
  for (int i = 0; i < 8; ++i) {
    int cx = (int)((px[i] - xmin) * invw); cx = cx < 0 ? 0 : (cx > G - 1 ? G - 1 : cx);
    int cy = (int)((py[i] - ymin) * invw); cy = cy < 0 ? 0 : (cy > G - 1 ? G - 1 : cy);
    cell[i] = cy * G + cx;
    atomicAdd(&hist[cell[i]], 1u);
  }
  __syncthreads();

  // 3-barrier prefix scan over 4096 cell counts (4 cells per thread)
  unsigned int h0 = hist[4 * t], h1 = hist[4 * t + 1], h2 = hist[4 * t + 2], h3 = hist[4 * t + 3];
  unsigned int s = h0 + h1 + h2 + h3;
  unsigned int ps = s;
#pragma unroll
  for (int j = 1; j < 64; j <<= 1) {
    unsigned int o = __shfl_up(ps, j, 64);
    if (lane >= j) ps += o;
  }
  if (lane == 63) wsum[wv] = ps;
  __syncthreads();
  if (t == 0) {
    unsigned int a = 0;
    for (int i = 0; i < 16; ++i) { unsigned int v = wsum[i]; wsum[i] = a; a += v; }
  }
  __syncthreads();
  unsigned int ex = wsum[wv] + ps - s;

  unsigned short* cs = (unsigned short*)(ws + WS_CS);
  cs[4 * t]     = (unsigned short)ex;
  cs[4 * t + 1] = (unsigned short)(ex + h0);
  cs[4 * t + 2] = (unsigned short)(ex + h0 + h1);
  cs[4 * t + 3] = (unsigned short)(ex + h0 + h1 + h2);
  if (t == 0) cs[NC] = (unsigned short)NPTS;
  hist[4 * t] = ex; hist[4 * t + 1] = ex + h0;
  hist[4 * t + 2] = ex + h0 + h1; hist[4 * t + 3] = ex + h0 + h1 + h2;
  __syncthreads();           // hist[] = starts (global prefix), visible to all

  // ---- per-cell certified scan radius (hist read-only here) ----
  // Expand r until B(cell,r) holds >=16 points. Any query q in this cell has
  // its top-16 within (r+1)*w*sqrt(2); points outside B(cell,r'') are
  // >= (r''-0)*w... specifically >= r''*w - w*0 (cell-gap bound) with
  // r'' = ceil(1.41422*(r+1)) + 1 giving >= 0.58w strict margin.
  unsigned char* sr = (unsigned char*)(ws + WS_SR);
  for (int c = t; c < NC; c += TPB_A) {
    int ccx = c & (G - 1), ccy = c >> 6;
    int r = 0;
    for (;; ++r) {
      int x0 = ccx - r; if (x0 < 0) x0 = 0;
      int x1 = ccx + r; if (x1 > G - 1) x1 = G - 1;
      int y0 = ccy - r; if (y0 < 0) y0 = 0;
      int y1 = ccy + r; if (y1 > G - 1) y1 = G - 1;
      int cnt2 = 0;
      for (int ry = y0; ry <= y1; ++ry) {
        int ia = ry * G + x0;
        int ib = ry * G + x1 + 1;
        int sa = (int)hist[ia];
        int sb = (ib >= NC) ? NPTS : (int)hist[ib];
        cnt2 += sb - sa;
      }
      if (cnt2 >= 16 || (x0 == 0 && y0 == 0 && x1 == G - 1 && y1 == G - 1)) break;
    }
    int rr = (int)ceilf(1.41422f * (float)(r + 1)) + 1;
    if (rr > 63) rr = 63;
    sr[c] = (unsigned char)rr;
  }
  __syncthreads();           // radius reads complete before scatter mutates hist

  float2* crd = (float2*)(ws + WS_CRD);
  unsigned short* sidx = (unsigned short*)(ws + WS_SIDX);
#pragma unroll
  for (int i = 0; i < 8; ++i) {
    int idx = t + i * TPB_A;
    unsigned int pos = atomicAdd(&hist[cell[i]], 1u);
    crd[pos] = make_float2(px[i], py[i]);
    sidx[pos] = (unsigned short)(idx | ((y[idx] & 1) << 13));
  }
}

// ---------------- Kernel B: single-level query, cell-sorted order ----------------
__global__ __launch_bounds__(TPB)
void query_kernel(const unsigned char* __restrict__ ws,
                  float* __restrict__ out) {
  __shared__ float2 crd_l[NPTS];               // 64 KB cell-sorted coords
  __shared__ unsigned short cs_l[NC + 8];      // 8.2 KB cell starts
  __shared__ unsigned int buf[WPB][SEG];       // 2 KB candidate positions

  const int t = threadIdx.x;
  const float4* g4 = (const float4*)(ws + WS_CRD);
#pragma unroll
  for (int i = t; i < NPTS / 2; i += TPB) ((float4*)crd_l)[i] = g4[i];
  const unsigned int* gcs = (const unsigned int*)(ws + WS_CS);
  for (int i = t; i < (NC + 8) / 2; i += TPB) ((unsigned int*)cs_l)[i] = gcs[i];
  __syncthreads();

  const float* hdr = (const float*)ws;
  const float xmin = hdr[0], ymin = hdr[1], invw = hdr[2];
  const unsigned short* gsidx = (const unsigned short*)(ws + WS_SIDX);
  const unsigned char* gsr = ws + WS_SR;

  const int wv = t >> 6, lane = t & 63;
  const unsigned long long lmask = (1ull << lane) - 1ull;

  // Cell-sorted query order: wave g handles sorted position g. Neighboring
  // waves get spatially-adjacent queries => similar radii => balanced blocks.
  const int gw = (int)blockIdx.x * WPB + wv;
  const float2 xq = crd_l[gw];                       // exact fp32 original coords
  const int q_orig = (int)(gsidx[gw] & 0x1FFFu);
  int qcx = (int)((xq.x - xmin) * invw); qcx = qcx < 0 ? 0 : (qcx > G - 1 ? G - 1 : qcx);
  int qcy = (int)((xq.y - ymin) * invw); qcy = qcy < 0 ? 0 : (qcy > G - 1 ? G - 1 : qcy);
  const int rr = (int)gsr[qcy * G + qcx];            // precomputed certified radius

  int bx0 = qcx - rr; if (bx0 < 0) bx0 = 0;
  int bx1 = qcx + rr; if (bx1 > G - 1) bx1 = G - 1;
  int by0 = qcy - rr; if (by0 < 0) by0 = 0;
  int by1 = qcy + rr; if (by1 > G - 1) by1 = G - 1;
  const int rows = by1 - by0 + 1;                    // <= 64

  // lane-prefetched row spans (one parallel cs_l read pair)
  const int myrow = by0 + lane;
  const bool rv = lane < rows;
  int ms0 = rv ? (int)cs_l[myrow * G + bx0] : 0;
  int mn  = rv ? (int)cs_l[myrow * G + bx1 + 1] - ms0 : 0;
  int inc = mn;
#pragma unroll
  for (int j = 1; j < 64; j <<= 1) {
    int o = __shfl_up(inc, j, 64);
    if (lane >= j) inc += o;
  }
  int cex = inc - mn;                                // exclusive point-rank prefix

  // ---- scan A: single certified block, round-robin point partition ----
  float m = 3e38f;
  for (int i = 0; i < rows; ++i) {
    int s0 = __shfl(ms0, i, 64);
    int n  = __shfl(mn, i, 64);
    int cb = __shfl(cex, i, 64);
    int base = (lane - cb) & 63;
    int iters = (n + 63) >> 6;
    for (int it = 0; it < iters; ++it) {
      int j = (it << 6) + base;
      bool a = j < n;
      float2 pp = crd_l[a ? s0 + j : 0];
      float dx = xq.x - pp.x, dy = xq.y - pp.y;
      float d = __builtin_fmaf(dx, dx, dy * dy);
      if (a) m = fminf(m, d);
    }
  }

  // T16 = 16th-smallest lane-min (>=16 distinct scanned pts, >=15 non-self)
  unsigned int srt = bitonic_sort_u32(__float_as_uint(m), lane);
  const float T16 = __uint_as_float(__shfl(srt, KNN, 64));
  const float T = T16 * (1.0f + 1e-5f) + 1e-30f;     // covers fp32 eval noise

  // ---- scan B: collect positions with d32 <= T (spans from registers) ----
  int cnt = 0;
  for (int i = 0; i < rows; ++i) {
    int s0 = __shfl(ms0, i, 64);
    int n  = __shfl(mn, i, 64);
    int iters = (n + 63) >> 6;
    for (int it = 0; it < iters; ++it) {
      int j = (it << 6) + lane;
      bool a = j < n;
      float2 pp = crd_l[a ? s0 + j : 0];
      float dx = xq.x - pp.x, dy = xq.y - pp.y;
      float d = __builtin_fmaf(dx, dx, dy * dy);
      bool c = a && (d <= T);
      unsigned long long kb = __ballot(c);
      if (c) {
        int o = cnt + __popcll(kb & lmask);
        if (o < SEG) buf[wv][o] = (unsigned int)(s0 + j);
      }
      cnt += __popcll(kb);
    }
  }

  // ---- exact fp64 keys + shfl-rank selection (no bitonic chain) ----
  int C2 = (cnt > SEG) ? SEG : cnt;                  // >=16 certified
  unsigned long long kv = ~0ull;
  if (lane < C2) {
    int pos = (int)buf[wv][lane];
    float2 pj = crd_l[pos];                          // exact fp32 originals
    unsigned int si = gsidx[pos];
    int jj = (int)(si & 0x1FFFu);
    unsigned long long lbl = (si >> 13) & 1u;
    double dx = (double)xq.x - (double)pj.x;         // exact fp32->fp64
    double dy = (double)xq.y - (double)pj.y;
    double dd = dx * dx + dy * dy;                   // rel err ~1e-16
    kv = ((unsigned long long)__double_as_longlong(dd) & ~0x3FFFull) |
         ((unsigned long long)jj << 1) | lbl;        // unique keys; lower idx wins ties
    if (jj == q_orig) kv = ~0ull;                    // drop self
  }
  int rank = 0;
  for (int j = 0; j < C2; ++j) {                     // independent shfls, pipelined
    unsigned long long kj = __shfl(kv, j, 64);
    rank += (kj < kv) ? 1 : 0;
  }
  unsigned long long vm = __ballot((lane < C2) && (rank < KNN) && (kv & 1ull));
  if (lane == 0) out[q_orig] = (__popcll(vm) >= 8) ? 1.0f : 0.0f;   // sum > 7.5
}

extern "C" void kernel_launch(void* const* d_in, const int* in_sizes, int n_in,
                              void* d_out, int out_size, void* d_ws, size_t ws_size,
                              hipStream_t stream) {
  const float* x = (const float*)d_in[0];
  const int* y = (const int*)d_in[1];
  float* out = (float*)d_out;
  unsigned char* ws = (unsigned char*)d_ws;
  hipLaunchKernelGGL(build_kernel, dim3(1), dim3(TPB_A), 0, stream, x, y, ws);
  hipLaunchKernelGGL(query_kernel, dim3(NPTS / WPB), dim3(TPB), 0, stream,
                     ws, out);
}